// Round 1
// baseline (471.807 us; speedup 1.0000x reference)
//
#include <hip/hip_runtime.h>

#define NFEAT 2000
#define NMID  1998       // number of middle cores
#define BDIM  16
#define BATCH 4096
#define SPB   16         // samples per block
#define TCH   16         // chain steps staged per chunk
#define HALF  999        // steps per direction (999 + 999 = 1998)
#define RP    20         // padded row length in floats (bank-conflict-free, 16B aligned)

// Each block: 16 samples, 512 threads.
//   dir = tid>>8        : 0 = left (forward) chain, 1 = right (backward) chain
//   slot = (tid&255)>>4 : sample slot 0..15
//   t = tid&15          : bond-dimension lane 0..15
// A sample's 16 threads of one direction live in one wave (wave = 4 slots x 16 t),
// so the v-exchange through LDS is wave-synchronous (same-wave DS ops are ordered).
__global__ __launch_bounds__(512, 1)
void mps_chain_kernel(const float* __restrict__ x,    // [BATCH][NFEAT]
                      const float* __restrict__ cf,   // [1][2][16]
                      const float* __restrict__ cm,   // [NMID][16][2][16]
                      const float* __restrict__ cl,   // [16][2][1]
                      float* __restrict__ out)        // [BATCH]
{
    // cores[dir][s][p][row][RP]:
    //   dir=0 (left, transposed): row = e, contents = cm[m][d][p][e] over d (column of M)
    //   dir=1 (right, natural)  : row = d, contents = cm[m][d][p][e] over e (row of M)
    __shared__ float cores[2][TCH][2][BDIM][RP];   // 2*16*2*16*20*4 = 81920 B
    __shared__ float vx[2][SPB][RP];               // v exchange, 2560 B
    __shared__ float xs[2][SPB][TCH];              // staged x, 2048 B

    const int tid  = threadIdx.x;
    const int dir  = tid >> 8;
    const int idx  = tid & 255;
    const int slot = idx >> 4;
    const int t    = idx & 15;
    const int b    = blockIdx.x * SPB + slot;
    const size_t xrow = (size_t)b * NFEAT;

    // ---- boundary vector init ----
    float v;
    {
        const float xv = x[xrow + (dir ? (NFEAT - 1) : 0)];
        const float th = xv * 1.57079632679f;
        const float c = __cosf(th), s = __sinf(th);
        // left:  v0[d] = cf[0][0][d]*c + cf[0][1][d]*s
        // right: w[d]  = cl[d][0]*c + cl[d][1]*s
        v = dir ? (cl[2 * t] * c + cl[2 * t + 1] * s)
                : (cf[t] * c + cf[16 + t] * s);
    }

    for (int base = 0; base < HALF; base += TCH) {
        const int nsteps = (HALF - base) < TCH ? (HALF - base) : TCH;
        __syncthreads();   // previous chunk's compute done before restaging

        // ---- stage x: one element per thread ----
        {
            const int k = base + t;   // step index this thread stages
            if (k < HALF) {
                // left step k uses feature 1+k; right step k uses feature NMID-k
                const int feat = dir ? (NMID - k) : (1 + k);
                xs[dir][slot][t] = x[xrow + feat];
            }
        }

        // ---- stage cores: each side nsteps*512 floats; 4 float4 per thread per side ----
        #pragma unroll
        for (int side = 0; side < 2; ++side) {
            #pragma unroll
            for (int k = 0; k < 4; ++k) {
                const int id = tid + 512 * k;       // float4 id within side
                const int s  = id >> 7;             // step within chunk
                if (s < nsteps) {
                    const int r  = id & 127;        // float4 within step (128 per step)
                    const int d  = r >> 3;
                    const int p  = (r >> 2) & 1;
                    const int e4 = (r & 3) * 4;
                    // left consumes core m = base+s ; right consumes m = NMID-1-(base+s)
                    const int m  = side ? (NMID - 1 - (base + s)) : (base + s);
                    const float4 val = *(const float4*)(cm + (size_t)m * 512 + 4 * r);
                    if (side == 0) {   // transpose: [p][e][d]
                        cores[0][s][p][e4 + 0][d] = val.x;
                        cores[0][s][p][e4 + 1][d] = val.y;
                        cores[0][s][p][e4 + 2][d] = val.z;
                        cores[0][s][p][e4 + 3][d] = val.w;
                    } else {           // natural: [p][d][e]
                        *(float4*)&cores[1][s][p][d][e4] = val;
                    }
                }
            }
        }
        __syncthreads();

        // ---- inner chain steps ----
        #pragma unroll 4
        for (int s = 0; s < nsteps; ++s) {
            const float xv  = xs[dir][slot][s];
            const float th  = xv * 1.57079632679f;
            const float cth = __cosf(th);
            const float sth = __sinf(th);

            // wave-synchronous v exchange (same-wave DS ops are in order)
            vx[dir][slot][t] = v;
            const float4 va = *(const float4*)&vx[dir][slot][0];
            const float4 vb = *(const float4*)&vx[dir][slot][4];
            const float4 vc = *(const float4*)&vx[dir][slot][8];
            const float4 vd = *(const float4*)&vx[dir][slot][12];

            const float* r0 = &cores[dir][s][0][t][0];
            const float* r1 = &cores[dir][s][1][t][0];
            const float4 m0 = *(const float4*)(r0);
            const float4 m1 = *(const float4*)(r0 + 4);
            const float4 m2 = *(const float4*)(r0 + 8);
            const float4 m3 = *(const float4*)(r0 + 12);
            const float4 n0 = *(const float4*)(r1);
            const float4 n1 = *(const float4*)(r1 + 4);
            const float4 n2 = *(const float4*)(r1 + 8);
            const float4 n3 = *(const float4*)(r1 + 12);

            float a0 = m0.x * va.x + m0.y * va.y + m0.z * va.z + m0.w * va.w;
            a0 += m1.x * vb.x + m1.y * vb.y + m1.z * vb.z + m1.w * vb.w;
            a0 += m2.x * vc.x + m2.y * vc.y + m2.z * vc.z + m2.w * vc.w;
            a0 += m3.x * vd.x + m3.y * vd.y + m3.z * vd.z + m3.w * vd.w;
            float a1 = n0.x * va.x + n0.y * va.y + n0.z * va.z + n0.w * va.w;
            a1 += n1.x * vb.x + n1.y * vb.y + n1.z * vb.z + n1.w * vb.w;
            a1 += n2.x * vc.x + n2.y * vc.y + n2.z * vc.z + n2.w * vc.w;
            a1 += n3.x * vd.x + n3.y * vd.y + n3.z * vd.z + n3.w * vd.w;

            v = cth * a0 + sth * a1;
        }
    }

    // ---- join the two half-chains: out[b] = sum_t L[t]*R[t] ----
    __syncthreads();
    if (dir == 1) vx[1][slot][t] = v;
    __syncthreads();
    if (dir == 0) {
        float p = v * vx[1][slot][t];
        p += __shfl_xor(p, 1);
        p += __shfl_xor(p, 2);
        p += __shfl_xor(p, 4);
        p += __shfl_xor(p, 8);
        if (t == 0) out[b] = p;
    }
}

extern "C" void kernel_launch(void* const* d_in, const int* in_sizes, int n_in,
                              void* d_out, int out_size, void* d_ws, size_t ws_size,
                              hipStream_t stream) {
    const float* x  = (const float*)d_in[0];
    const float* cf = (const float*)d_in[1];
    const float* cm = (const float*)d_in[2];
    const float* cl = (const float*)d_in[3];
    float* out = (float*)d_out;
    dim3 grid(BATCH / SPB);   // 256 blocks (one per CU)
    dim3 block(512);
    hipLaunchKernelGGL(mps_chain_kernel, grid, block, 0, stream, x, cf, cm, cl, out);
}

// Round 2
// 321.746 us; speedup vs baseline: 1.4664x; 1.4664x over previous
//
#include <hip/hip_runtime.h>

#define NFEAT 2000
#define NMID  1998
#define BATCH 4096
#define PI_2  1.57079632679489662f

#define PAIR_FLOATS  1280            // [4][16][20] padded
#define REGION_PAIRS 500             // 499 real + 1 pad
#define REGION_FLOATS (REGION_PAIRS * PAIR_FLOATS)
#define TCH 4                        // pairs per staged chunk
#define CHUNK_FLOATS (TCH * PAIR_FLOATS)   // 5120
#define NCHUNK 125                   // 124 full (4 iters) + tail (3 iters) = 499

// ---------------- precompute: pair products into d_ws ----------------
// pair i (0..997): steps s1=2i+1, s2=2i+2.  P_k[d][e] = sum_m M1[d][p1][m]*M2[m][p2][e], k=p1*2+p2
// left region  (i<=498): store transposed rows:  ws[i*1280 + k*320 + e*20 + d] = P_k[d][e]
// right region (i>=499): j=997-i, natural rows:  ws[RF + j*1280 + k*320 + d*20 + e] = P_k[d][e]
__global__ __launch_bounds__(64, 1)
void precompute_pairs(const float* __restrict__ cm, float* __restrict__ ws)
{
    __shared__ float M1[512], M2[512];
    const int i = blockIdx.x;
    const int tid = threadIdx.x;
    const float4* g1 = (const float4*)(cm + (size_t)(2 * i + 1) * 512);
    const float4* g2 = (const float4*)(cm + (size_t)(2 * i + 2) * 512);
    ((float4*)M1)[tid]      = g1[tid];
    ((float4*)M1)[tid + 64] = g1[tid + 64];
    ((float4*)M2)[tid]      = g2[tid];
    ((float4*)M2)[tid + 64] = g2[tid + 64];
    __syncthreads();
    const int k  = tid >> 4;
    const int p1 = k >> 1, p2 = k & 1;
    const int r  = tid & 15;
    if (i <= 498) {
        // thread owns column e=r of P_k -> row r of P_k^T
        float o[16];
        #pragma unroll
        for (int d = 0; d < 16; ++d) {
            float acc = 0.f;
            #pragma unroll
            for (int m = 0; m < 16; ++m)
                acc += M1[d * 32 + p1 * 16 + m] * M2[m * 32 + p2 * 16 + r];
            o[d] = acc;
        }
        float* dst = ws + (size_t)i * PAIR_FLOATS + k * 320 + r * 20;
        #pragma unroll
        for (int d = 0; d < 16; ++d) dst[d] = o[d];
    } else {
        const int j = 997 - i;
        // thread owns row d=r of P_k
        float o[16];
        #pragma unroll
        for (int e = 0; e < 16; ++e) o[e] = 0.f;
        #pragma unroll
        for (int m = 0; m < 16; ++m) {
            const float a = M1[r * 32 + p1 * 16 + m];
            #pragma unroll
            for (int e = 0; e < 16; ++e)
                o[e] += a * M2[m * 32 + p2 * 16 + e];
        }
        float* dst = ws + (size_t)REGION_FLOATS + (size_t)j * PAIR_FLOATS + k * 320 + r * 20;
        #pragma unroll
        for (int e = 0; e < 16; ++e) dst[e] = o[e];
    }
}

__device__ __forceinline__ float d16(float4 q0, float4 q1, float4 q2, float4 q3,
                                     float4 a0, float4 a1, float4 a2, float4 a3)
{
    return q0.x * a0.x + q0.y * a0.y + q0.z * a0.z + q0.w * a0.w
         + q1.x * a1.x + q1.y * a1.y + q1.z * a1.z + q1.w * a1.w
         + q2.x * a2.x + q2.y * a2.y + q2.z * a2.z + q2.w * a2.w
         + q3.x * a3.x + q3.y * a3.y + q3.z * a3.z + q3.w * a3.w;
}

// ---------------- main: bidirectional paired chain, ILP=2 samples/lane ----------------
// block = 256 thr: dir = tid>>7 (wave-pure), 8 groups x 16 lanes per dir, 2 samples per group.
__global__ __launch_bounds__(256, 1)
void mps_pair_kernel(const float* __restrict__ x,  const float* __restrict__ cf,
                     const float* __restrict__ cm, const float* __restrict__ cl,
                     const float* __restrict__ ws, float* __restrict__ out)
{
    __shared__ float coresA[2][CHUNK_FLOATS];   // [dir] buffer 0
    __shared__ float coresB[2][CHUNK_FLOATS];   // [dir] buffer 1 (distinct object: no alias stall)
    __shared__ float vx[2][8][2][20];
    __shared__ float xsA[2][128];
    __shared__ float xsB[2][128];

    const int tid = threadIdx.x;
    const int dir = tid >> 7;
    const int l   = tid & 127;
    const int g   = l >> 4;
    const int t   = l & 15;
    const int wvw = l >> 6;          // wave within dir
    const int t8  = l & 7;
    const int ab  = (l >> 3) & 1;
    const int bA  = blockIdx.x * 16 + g * 2;
    const size_t xrA = (size_t)bA * NFEAT;
    const size_t xrB = xrA + NFEAT;
    const size_t xrS = (size_t)(bA + ab) * NFEAT;   // row this lane stages xs from

    const float* wsreg = ws + (size_t)dir * REGION_FLOATS;

    // ---- init: boundary vector + one plain step ----
    float vA, vB;
    {
        const size_t bfeat = dir ? (NFEAT - 1) : 0;
        const size_t pfeat = dir ? (NFEAT - 2) : 1;
        const float thA = x[xrA + bfeat] * PI_2, thB = x[xrB + bfeat] * PI_2;
        const float cA = __cosf(thA), sA = __sinf(thA);
        const float cB = __cosf(thB), sB = __sinf(thB);
        const float phA = x[xrA + pfeat] * PI_2, phB = x[xrB + pfeat] * PI_2;
        const float c1A = __cosf(phA), s1A = __sinf(phA);
        const float c1B = __cosf(phB), s1B = __sinf(phB);
        float accA = 0.f, accB = 0.f;
        if (dir == 0) {
            // v0[d] = cf[0][p][d].q ; plain step mid-core 0, column t
            #pragma unroll
            for (int d = 0; d < 16; ++d) {
                const float m0 = cm[d * 32 + t];
                const float m1 = cm[d * 32 + 16 + t];
                const float v0A = cf[d] * cA + cf[16 + d] * sA;
                const float v0B = cf[d] * cB + cf[16 + d] * sB;
                accA += v0A * (c1A * m0 + s1A * m1);
                accB += v0B * (c1B * m0 + s1B * m1);
            }
        } else {
            // w0[e] = cl[e][p].q ; plain step mid-core 1997, row t
            const float* M = cm + (size_t)1997 * 512 + t * 32;
            #pragma unroll
            for (int e = 0; e < 16; ++e) {
                const float m0 = M[e];
                const float m1 = M[16 + e];
                const float w0A = cl[2 * e] * cA + cl[2 * e + 1] * sA;
                const float w0B = cl[2 * e] * cB + cl[2 * e + 1] * sB;
                accA += (c1A * m0 + s1A * m1) * w0A;
                accB += (c1B * m0 + s1B * m1) * w0B;
            }
        }
        vA = accA; vB = accB;
    }

    float* vxA = &vx[dir][g][0][0];
    float* vxB = &vx[dir][g][1][0];

    auto stage = [&](int cc, float* dcore, float* dxs) {
        const float* src = wsreg + (size_t)cc * CHUNK_FLOATS + wvw * 256 + (l & 63) * 4;
        float* db = dcore + wvw * 256;
        #pragma unroll
        for (int k = 0; k < 10; ++k)
            __builtin_amdgcn_global_load_lds(src + k * 512, db + k * 512, 16, 0, 0);
        const int feat = (dir == 0) ? (8 * cc + 2 + t8)
                                    : (1996 - 8 * cc - (t8 & ~1) + (t8 & 1));
        __builtin_amdgcn_global_load_lds(x + xrS + feat, dxs + wvw * 64, 4, 0, 0);
    };

    auto iter = [&](const float* corep, const float* xsg, int jj) {
        vxA[t] = vA;
        vxB[t] = vB;
        const float xa1 = xsg[2 * jj],     xa2 = xsg[2 * jj + 1];
        const float xb1 = xsg[8 + 2 * jj], xb2 = xsg[8 + 2 * jj + 1];
        const float ca1 = __cosf(xa1 * PI_2), sa1 = __sinf(xa1 * PI_2);
        const float ca2 = __cosf(xa2 * PI_2), sa2 = __sinf(xa2 * PI_2);
        const float cb1 = __cosf(xb1 * PI_2), sb1 = __sinf(xb1 * PI_2);
        const float cb2 = __cosf(xb2 * PI_2), sb2 = __sinf(xb2 * PI_2);
        const float wA0 = ca1 * ca2, wA1 = ca1 * sa2, wA2 = sa1 * ca2, wA3 = sa1 * sa2;
        const float wB0 = cb1 * cb2, wB1 = cb1 * sb2, wB2 = sb1 * cb2, wB3 = sb1 * sb2;

        const float4 a0 = *(const float4*)(vxA + 0),  a1 = *(const float4*)(vxA + 4);
        const float4 a2 = *(const float4*)(vxA + 8),  a3 = *(const float4*)(vxA + 12);
        const float4 b0 = *(const float4*)(vxB + 0),  b1 = *(const float4*)(vxB + 4);
        const float4 b2 = *(const float4*)(vxB + 8),  b3 = *(const float4*)(vxB + 12);

        const float* r = corep + jj * 1280 + t * 20;
        float4 q0, q1, q2, q3;
        q0 = *(const float4*)(r);      q1 = *(const float4*)(r + 4);
        q2 = *(const float4*)(r + 8);  q3 = *(const float4*)(r + 12);
        const float dA0 = d16(q0, q1, q2, q3, a0, a1, a2, a3);
        const float dB0 = d16(q0, q1, q2, q3, b0, b1, b2, b3);
        r += 320;
        q0 = *(const float4*)(r);      q1 = *(const float4*)(r + 4);
        q2 = *(const float4*)(r + 8);  q3 = *(const float4*)(r + 12);
        const float dA1 = d16(q0, q1, q2, q3, a0, a1, a2, a3);
        const float dB1 = d16(q0, q1, q2, q3, b0, b1, b2, b3);
        r += 320;
        q0 = *(const float4*)(r);      q1 = *(const float4*)(r + 4);
        q2 = *(const float4*)(r + 8);  q3 = *(const float4*)(r + 12);
        const float dA2 = d16(q0, q1, q2, q3, a0, a1, a2, a3);
        const float dB2 = d16(q0, q1, q2, q3, b0, b1, b2, b3);
        r += 320;
        q0 = *(const float4*)(r);      q1 = *(const float4*)(r + 4);
        q2 = *(const float4*)(r + 8);  q3 = *(const float4*)(r + 12);
        const float dA3 = d16(q0, q1, q2, q3, a0, a1, a2, a3);
        const float dB3 = d16(q0, q1, q2, q3, b0, b1, b2, b3);

        vA = (wA0 * dA0 + wA1 * dA1) + (wA2 * dA2 + wA3 * dA3);
        vB = (wB0 * dB0 + wB1 * dB1) + (wB2 * dB2 + wB3 * dB3);
    };

    // ---- prologue ----
    stage(0, &coresA[dir][0], &xsA[dir][0]);
    __syncthreads();

    // ---- main loop: 124 full chunks ----
    for (int c = 0; c < NCHUNK - 1; ++c) {
        const int bsel = c & 1;
        float* curC = bsel ? &coresB[dir][0] : &coresA[dir][0];
        const float* curX = bsel ? &xsB[dir][0] : &xsA[dir][0];
        float* nxtC = bsel ? &coresA[dir][0] : &coresB[dir][0];
        float* nxtX = bsel ? &xsA[dir][0] : &xsB[dir][0];
        stage(c + 1, nxtC, nxtX);
        const float* xsg = curX + g * 16;
        iter(curC, xsg, 0);
        iter(curC, xsg, 1);
        iter(curC, xsg, 2);
        iter(curC, xsg, 3);
        __syncthreads();   // drains glds (vmcnt 0) + publishes next buffer
    }
    // ---- tail chunk (c=124, parity 0 -> A), 3 iters ----
    {
        const float* curC = &coresA[dir][0];
        const float* xsg  = &xsA[dir][0] + g * 16;
        iter(curC, xsg, 0);
        iter(curC, xsg, 1);
        iter(curC, xsg, 2);
    }

    // ---- join: out[b] = L . R ----
    __syncthreads();
    if (dir == 1) { vxA[t] = vA; vxB[t] = vB; }
    __syncthreads();
    if (dir == 0) {
        const float rA = vx[1][g][0][t];
        const float rB = vx[1][g][1][t];
        float pA = vA * rA, pB = vB * rB;
        pA += __shfl_xor(pA, 1); pA += __shfl_xor(pA, 2);
        pA += __shfl_xor(pA, 4); pA += __shfl_xor(pA, 8);
        pB += __shfl_xor(pB, 1); pB += __shfl_xor(pB, 2);
        pB += __shfl_xor(pB, 4); pB += __shfl_xor(pB, 8);
        if (t == 0) { out[bA] = pA; out[bA + 1] = pB; }
    }
}

extern "C" void kernel_launch(void* const* d_in, const int* in_sizes, int n_in,
                              void* d_out, int out_size, void* d_ws, size_t ws_size,
                              hipStream_t stream) {
    const float* x  = (const float*)d_in[0];
    const float* cf = (const float*)d_in[1];
    const float* cm = (const float*)d_in[2];
    const float* cl = (const float*)d_in[3];
    float* ws  = (float*)d_ws;      // needs 2*500*1280*4 = 5.12 MB
    float* out = (float*)d_out;
    hipLaunchKernelGGL(precompute_pairs, dim3(998), dim3(64), 0, stream, cm, ws);
    hipLaunchKernelGGL(mps_pair_kernel, dim3(256), dim3(256), 0, stream,
                       x, cf, cm, cl, ws, out);
}

// Round 3
// 20.161 us; speedup vs baseline: 23.4018x; 15.9587x over previous
//
#include <hip/hip_runtime.h>

#define NFEAT 2000
#define NMID  1998       // number of middle cores
#define BDIM  16
#define BATCH 4096
#define SPB   16         // samples per block
#define TCH   16         // chain steps staged per chunk
#define HALF  999        // steps per direction (999 + 999 = 1998)
#define RP    20         // padded row length in floats (bank-conflict-free, 16B aligned)

// Each block: 16 samples, 512 threads.
//   dir = tid>>8        : 0 = left (forward) chain, 1 = right (backward) chain
//   slot = (tid&255)>>4 : sample slot 0..15
//   t = tid&15          : bond-dimension lane 0..15
// A sample's 16 threads of one direction live in one wave, so the v-exchange
// through LDS is wave-synchronous.
//
// EARLY EXIT: v's norm contracts by ~0.04 per step for this model family
// (0.01-scale cores, unit-norm qubit), so v underflows to EXACT fp32 zero
// after a few dozen steps. Zero is an absorbing state of the recurrence
// (M^T * 0 == 0 exactly, and the final join gives exactly 0), so once every
// lane in the block holds v == 0.0f the remaining chain is provably a no-op.
// The vote is exact and input-agnostic: non-decaying inputs simply run the
// full chain.
__global__ __launch_bounds__(512, 1)
void mps_chain_kernel(const float* __restrict__ x,    // [BATCH][NFEAT]
                      const float* __restrict__ cf,   // [1][2][16]
                      const float* __restrict__ cm,   // [NMID][16][2][16]
                      const float* __restrict__ cl,   // [16][2][1]
                      float* __restrict__ out)        // [BATCH]
{
    // cores[dir][s][p][row][RP]:
    //   dir=0 (left, transposed): row = e, contents = cm[m][d][p][e] over d
    //   dir=1 (right, natural)  : row = d, contents = cm[m][d][p][e] over e
    __shared__ float cores[2][TCH][2][BDIM][RP];   // 81920 B
    __shared__ float vx[2][SPB][RP];
    __shared__ float xs[2][SPB][TCH];

    const int tid  = threadIdx.x;
    const int dir  = tid >> 8;
    const int idx  = tid & 255;
    const int slot = idx >> 4;
    const int t    = idx & 15;
    const int b    = blockIdx.x * SPB + slot;
    const size_t xrow = (size_t)b * NFEAT;

    // ---- boundary vector init ----
    float v;
    {
        const float xv = x[xrow + (dir ? (NFEAT - 1) : 0)];
        const float th = xv * 1.57079632679f;
        const float c = __cosf(th), s = __sinf(th);
        v = dir ? (cl[2 * t] * c + cl[2 * t + 1] * s)
                : (cf[t] * c + cf[16 + t] * s);
    }

    for (int base = 0; base < HALF; base += TCH) {
        const int nsteps = (HALF - base) < TCH ? (HALF - base) : TCH;

        // ---- stage x: one element per thread ----
        {
            const int k = base + t;
            if (k < HALF) {
                const int feat = dir ? (NMID - k) : (1 + k);
                xs[dir][slot][t] = x[xrow + feat];
            }
        }

        // ---- stage cores ----
        #pragma unroll
        for (int side = 0; side < 2; ++side) {
            #pragma unroll
            for (int k = 0; k < 4; ++k) {
                const int id = tid + 512 * k;
                const int s  = id >> 7;
                if (s < nsteps) {
                    const int r  = id & 127;
                    const int d  = r >> 3;
                    const int p  = (r >> 2) & 1;
                    const int e4 = (r & 3) * 4;
                    const int m  = side ? (NMID - 1 - (base + s)) : (base + s);
                    const float4 val = *(const float4*)(cm + (size_t)m * 512 + 4 * r);
                    if (side == 0) {   // transpose: [p][e][d]
                        cores[0][s][p][e4 + 0][d] = val.x;
                        cores[0][s][p][e4 + 1][d] = val.y;
                        cores[0][s][p][e4 + 2][d] = val.z;
                        cores[0][s][p][e4 + 3][d] = val.w;
                    } else {           // natural: [p][d][e]
                        *(float4*)&cores[1][s][p][d][e4] = val;
                    }
                }
            }
        }
        __syncthreads();

        // ---- inner chain steps ----
        #pragma unroll 4
        for (int s = 0; s < nsteps; ++s) {
            const float xv  = xs[dir][slot][s];
            const float th  = xv * 1.57079632679f;
            const float cth = __cosf(th);
            const float sth = __sinf(th);

            vx[dir][slot][t] = v;
            const float4 va = *(const float4*)&vx[dir][slot][0];
            const float4 vb = *(const float4*)&vx[dir][slot][4];
            const float4 vc = *(const float4*)&vx[dir][slot][8];
            const float4 vd = *(const float4*)&vx[dir][slot][12];

            const float* r0 = &cores[dir][s][0][t][0];
            const float* r1 = &cores[dir][s][1][t][0];
            const float4 m0 = *(const float4*)(r0);
            const float4 m1 = *(const float4*)(r0 + 4);
            const float4 m2 = *(const float4*)(r0 + 8);
            const float4 m3 = *(const float4*)(r0 + 12);
            const float4 n0 = *(const float4*)(r1);
            const float4 n1 = *(const float4*)(r1 + 4);
            const float4 n2 = *(const float4*)(r1 + 8);
            const float4 n3 = *(const float4*)(r1 + 12);

            float a0 = m0.x * va.x + m0.y * va.y + m0.z * va.z + m0.w * va.w;
            a0 += m1.x * vb.x + m1.y * vb.y + m1.z * vb.z + m1.w * vb.w;
            a0 += m2.x * vc.x + m2.y * vc.y + m2.z * vc.z + m2.w * vc.w;
            a0 += m3.x * vd.x + m3.y * vd.y + m3.z * vd.z + m3.w * vd.w;
            float a1 = n0.x * va.x + n0.y * va.y + n0.z * va.z + n0.w * va.w;
            a1 += n1.x * vb.x + n1.y * vb.y + n1.z * vb.z + n1.w * vb.w;
            a1 += n2.x * vc.x + n2.y * vc.y + n2.z * vc.z + n2.w * vc.w;
            a1 += n3.x * vd.x + n3.y * vd.y + n3.z * vd.z + n3.w * vd.w;

            v = cth * a0 + sth * a1;
        }

        // ---- early-exit vote (also the inter-chunk barrier) ----
        // If v is exactly 0 for every lane in the block, the rest of the
        // chain is exactly 0: skip it. Exact for arbitrary inputs.
        if (__syncthreads_and(v == 0.0f)) break;
    }

    // ---- join the two half-chains: out[b] = sum_t L[t]*R[t] ----
    __syncthreads();
    if (dir == 1) vx[1][slot][t] = v;
    __syncthreads();
    if (dir == 0) {
        float p = v * vx[1][slot][t];
        p += __shfl_xor(p, 1);
        p += __shfl_xor(p, 2);
        p += __shfl_xor(p, 4);
        p += __shfl_xor(p, 8);
        if (t == 0) out[b] = p;
    }
}

extern "C" void kernel_launch(void* const* d_in, const int* in_sizes, int n_in,
                              void* d_out, int out_size, void* d_ws, size_t ws_size,
                              hipStream_t stream) {
    const float* x  = (const float*)d_in[0];
    const float* cf = (const float*)d_in[1];
    const float* cm = (const float*)d_in[2];
    const float* cl = (const float*)d_in[3];
    float* out = (float*)d_out;
    dim3 grid(BATCH / SPB);   // 256 blocks
    dim3 block(512);
    hipLaunchKernelGGL(mps_chain_kernel, grid, block, 0, stream, x, cf, cm, cl, out);
}